// Round 1
// baseline (4310.761 us; speedup 1.0000x reference)
//
#include <hip/hip_runtime.h>

typedef _Float16 half2_v __attribute__((ext_vector_type(2)));

#define NB   32
#define L1C  256
#define L2C  64
#define D1C  256
#define D2C  256
#define HD   256
#define PD   128
#define ID   512
#define GID  768

// ws layout, in half2 (4B) units
#define OFF_W2   0
#define OFF_WG   32768
#define OFF_WIH  163840
#define OFF_WHH  360448
#define N_PACK   458752
#define OFF_S2P_H 917504   // in _Float16 units (byte offset 1835008)

__device__ __forceinline__ float fdot2(half2_v a, half2_v b, float c) {
    return __builtin_amdgcn_fdot2(a, b, c, false);
}
__device__ __forceinline__ float fast_tanh(float x) {
    float e = __expf(2.0f * x);
    return 1.0f - 2.0f / (e + 1.0f);
}
__device__ __forceinline__ float fast_sigmoid(float x) {
    return 1.0f / (1.0f + __expf(-x));
}

// Pack weights: transposed (output-minor) fp16, consecutive-i pairs packed in half2.
__global__ void prep_pack(const float* __restrict__ W2, const float* __restrict__ Wg,
                          const float* __restrict__ wih, const float* __restrict__ whh,
                          half2_v* __restrict__ ws) {
    int idx = blockIdx.x * 256 + threadIdx.x;
    if (idx >= N_PACK) return;
    float a, c;
    if (idx < OFF_WG) {                       // W2p[i2][p] : W2 is [512][128]
        int t = idx, i2 = t >> 7, p = t & 127;
        a = W2[(2*i2)*PD + p]; c = W2[(2*i2+1)*PD + p];
    } else if (idx < OFF_WIH) {               // WgT[i2][o] : Wg is [512][512], need Wg[o][i]
        int t = idx - OFF_WG, i2 = t >> 9, o = t & 511;
        a = Wg[o*ID + 2*i2]; c = Wg[o*ID + 2*i2+1];
    } else if (idx < OFF_WHH) {               // wihT[i2][o] : w_ih is [768][512]
        int t = idx - OFF_WIH, i2 = t / GID, o = t - i2*GID;
        a = wih[o*ID + 2*i2]; c = wih[o*ID + 2*i2+1];
    } else {                                  // whhT[i2][o] : w_hh is [768][256]
        int t = idx - OFF_WHH, i2 = t / GID, o = t - i2*GID;
        a = whh[o*HD + 2*i2]; c = whh[o*HD + 2*i2+1];
    }
    half2_v r; r[0] = (_Float16)a; r[1] = (_Float16)c;
    ws[idx] = r;
}

// seq2 @ W1 -> [B][L2][P] fp16, chip-parallel
__global__ void prep_s2p(const float* __restrict__ seq2, const float* __restrict__ W1,
                         _Float16* __restrict__ outh) {
    int idx = blockIdx.x * 256 + threadIdx.x;   // 262144 total
    int p = idx & 127;
    int j = (idx >> 7) & 63;
    int b = idx >> 13;
    const float* s2 = seq2 + (b*L2C + j)*D2C;
    float acc = 0.f;
    #pragma unroll 8
    for (int d = 0; d < D2C; ++d) acc += s2[d] * W1[d*PD + p];
    outh[OFF_S2P_H + idx] = (_Float16)acc;
}

__global__ void __launch_bounds__(1024, 1) match_rnn(
    const float* __restrict__ seq1, const float* __restrict__ seq2,
    const float* __restrict__ mask1, const float* __restrict__ mask2,
    const float* __restrict__ v, const float* __restrict__ bg,
    const float* __restrict__ bih, const float* __restrict__ bhh,
    const half2_v* __restrict__ ws, float* __restrict__ out)
{
    const int b = blockIdx.x;
    const int tid = threadIdx.x;

    __shared__ _Float16 s_s2p[L2C][132];   // padded rows (132 halfs) vs bank conflicts
    __shared__ float s_neg[L2C];
    __shared__ float s_v[PD];
    __shared__ float s_bg[ID];
    __shared__ float s_bih[GID];
    __shared__ float s_bhh[GID];
    __shared__ float s_w[L2C];
    __shared__ float s_inf[ID];            // [x_t ; att] fp32 (pre-gate), overwritten by gated
    __shared__ float s_h[HD];
    __shared__ float s_gh[GID];
    __shared__ half2_v s_xh[ID/2];         // [x_t ; h] packed fp16 pairs
    __shared__ half2_v s_ia[ID/2];         // [x_t ; att] packed
    __shared__ half2_v s_ig[ID/2];         // gated inp packed
    __shared__ float s_red[3072];          // shared reduction scratch (phases are serialized)

    const half2_v* wW2 = ws + OFF_W2;
    const half2_v* wWG = ws + OFF_WG;
    const half2_v* wIH = ws + OFF_WIH;
    const half2_v* wHH = ws + OFF_WHH;
    const _Float16* s2ph = (const _Float16*)ws + OFF_S2P_H + b*(L2C*PD);

    // ---- prologue ----
    if (tid < ID)  s_bg[tid] = bg[tid];
    if (tid < GID) { s_bih[tid] = bih[tid]; s_bhh[tid] = bhh[tid]; }
    if (tid < PD)  s_v[tid] = v[tid];
    if (tid < L2C) s_neg[tid] = (mask2[b*L2C + tid] > 0.f) ? 0.f : -1e9f;
    if (tid < HD)  s_h[tid] = 0.f;
    if (tid >= 512 && tid < 640) {         // zero h-part of packed [x;h]
        half2_v z; z[0] = (_Float16)0.f; z[1] = (_Float16)0.f;
        s_xh[128 + (tid - 512)] = z;
    }
    if (tid >= 640 && tid < 768) {         // load x_0
        int k = tid - 640;
        float2 x2 = *(const float2*)(seq1 + (b*L1C)*D1C + 2*k);
        s_inf[2*k] = x2.x; s_inf[2*k+1] = x2.y;
        half2_v r; r[0] = (_Float16)x2.x; r[1] = (_Float16)x2.y;
        s_xh[k] = r; s_ia[k] = r;
    }
    for (int i = tid; i < L2C*PD; i += 1024) {
        s_s2p[i >> 7][i & 127] = s2ph[i];
    }
    __syncthreads();

    for (int t = 0; t < L1C; ++t) {
        // ---- B': gh = h@w_hh^T (threads 0..767) ; proj partials (768..1023) ----
        if (tid < GID) {
            float acc = s_bhh[tid];
            const half2_v* wp = wHH + tid;
            #pragma unroll 8
            for (int i2 = 0; i2 < 128; ++i2)
                acc = fdot2(wp[i2*GID], s_xh[128 + i2], acc);
            s_gh[tid] = acc;
        } else {
            int q = tid - GID;                 // 0..255
            int pp = q & 127, ks = q >> 7;     // 2-way K split
            float acc = 0.f;
            const half2_v* wp = wW2 + pp;
            int base = ks * 128;
            #pragma unroll 8
            for (int m = 0; m < 128; ++m)
                acc = fdot2(wp[(base + m)*PD], s_xh[base + m], acc);
            s_red[ks*128 + pp] = acc;
        }
        __syncthreads();

        // ---- C: scores_j = sum_p v_p * tanh(s2p[j][p] + proj[p]) ----
        {
            int j = tid >> 4, pk = tid & 15;
            const half2_v* row = (const half2_v*)&s_s2p[j][0];
            float acc = 0.f;
            #pragma unroll
            for (int q = 0; q < 4; ++q) {
                half2_v h2 = row[pk*4 + q];
                int p0 = pk*8 + q*2;
                float pr0 = s_red[p0]     + s_red[128 + p0];
                float pr1 = s_red[p0 + 1] + s_red[129 + p0];
                acc += fast_tanh((float)h2[0] + pr0) * s_v[p0];
                acc += fast_tanh((float)h2[1] + pr1) * s_v[p0 + 1];
            }
            acc += __shfl_down(acc, 8, 16);
            acc += __shfl_down(acc, 4, 16);
            acc += __shfl_down(acc, 2, 16);
            acc += __shfl_down(acc, 1, 16);
            if (pk == 0) s_w[j] = acc + s_neg[j];
        }
        __syncthreads();

        // ---- D: softmax over 64 (wave 0) ----
        if (tid < 64) {
            float sc = s_w[tid];
            float m = sc;
            #pragma unroll
            for (int off = 32; off > 0; off >>= 1) m = fmaxf(m, __shfl_xor(m, off));
            float e = __expf(sc - m);
            float s = e;
            #pragma unroll
            for (int off = 32; off > 0; off >>= 1) s += __shfl_xor(s, off);
            s_w[tid] = e / s;
        }
        __syncthreads();

        // ---- E: att partials, 4-way j split ----
        {
            int d = tid & 255, jk = tid >> 8;
            const float* s2 = seq2 + (b*L2C + jk*16)*D2C + d;
            float acc = 0.f;
            #pragma unroll
            for (int jj = 0; jj < 16; ++jj)
                acc += s_w[jk*16 + jj] * s2[jj*D2C];
            s_red[jk*256 + d] = acc;
        }
        __syncthreads();

        // ---- E2: reduce att, pack [x;att] ----
        if (tid < 256) {
            int d = tid;
            float att = s_red[d] + s_red[256+d] + s_red[512+d] + s_red[768+d];
            s_inf[256 + d] = att;
            float nb = __shfl_down(att, 1);
            if (!(d & 1)) {
                half2_v r; r[0] = (_Float16)att; r[1] = (_Float16)nb;
                s_ia[128 + (d >> 1)] = r;
            }
        }
        __syncthreads();

        // ---- F: gate partials  g[o] = sum_i inp[i]*Wg[o][i] ----
        {
            int o2 = tid & 255, ks = tid >> 8;
            float a0 = 0.f, a1 = 0.f;
            #pragma unroll 8
            for (int m = 0; m < 64; ++m) {
                int i2 = ks*64 + m;
                half2_v ia = s_ia[i2];
                a0 = fdot2(wWG[i2*ID + o2],        ia, a0);
                a1 = fdot2(wWG[i2*ID + o2 + 256],  ia, a1);
            }
            s_red[ks*ID + o2]       = a0;
            s_red[ks*ID + o2 + 256] = a1;
        }
        __syncthreads();

        // ---- F2: sigmoid gate, multiply, pack gated inp ----
        if (tid < ID) {
            int o = tid;
            float g = s_red[o] + s_red[512+o] + s_red[1024+o] + s_red[1536+o] + s_bg[o];
            float gate = fast_sigmoid(g);
            float ip = s_inf[o] * gate;
            s_inf[o] = ip;
            float nb = __shfl_down(ip, 1);
            if (!(o & 1)) {
                half2_v r; r[0] = (_Float16)ip; r[1] = (_Float16)nb;
                s_ig[o >> 1] = r;
            }
        }
        __syncthreads();

        // ---- G: gi partials  gi[o] = sum_i inp'[i]*w_ih[o][i] ----
        {
            int og = tid & 255, ks = tid >> 8;
            float a0 = 0.f, a1 = 0.f, a2 = 0.f;
            #pragma unroll 8
            for (int m = 0; m < 64; ++m) {
                int i2 = ks*64 + m;
                half2_v ig = s_ig[i2];
                a0 = fdot2(wIH[i2*GID + og],        ig, a0);
                a1 = fdot2(wIH[i2*GID + og + 256],  ig, a1);
                a2 = fdot2(wIH[i2*GID + og + 512],  ig, a2);
            }
            s_red[ks*GID + og]       = a0;
            s_red[ks*GID + og + 256] = a1;
            s_red[ks*GID + og + 512] = a2;
        }
        __syncthreads();

        // ---- H: GRU elementwise + output + h pack ; x_{t+1} prefetch ----
        if (tid < HD) {
            int o = tid;
            float gir = s_red[o]       + s_red[768+o]    + s_red[1536+o] + s_red[2304+o] + s_bih[o];
            float giz = s_red[256+o]   + s_red[1024+o]   + s_red[1792+o] + s_red[2560+o] + s_bih[256+o];
            float gin = s_red[512+o]   + s_red[1280+o]   + s_red[2048+o] + s_red[2816+o] + s_bih[512+o];
            float r_ = fast_sigmoid(gir + s_gh[o]);
            float z_ = fast_sigmoid(giz + s_gh[256+o]);
            float n_ = fast_tanh(gin + r_ * s_gh[512+o]);
            float hp = s_h[o];
            float hn = (1.f - z_)*n_ + z_*hp;
            s_h[o] = hn;
            out[(b*L1C + t)*HD + o] = hn * mask1[b*L1C + t];
            float nb = __shfl_down(hn, 1);
            if (!(o & 1)) {
                half2_v r; r[0] = (_Float16)hn; r[1] = (_Float16)nb;
                s_xh[128 + (o >> 1)] = r;
            }
        } else if (tid >= 256 && tid < 384) {
            if (t + 1 < L1C) {
                int k = tid - 256;
                float2 x2 = *(const float2*)(seq1 + (b*L1C + t + 1)*D1C + 2*k);
                s_inf[2*k] = x2.x; s_inf[2*k+1] = x2.y;
                half2_v r; r[0] = (_Float16)x2.x; r[1] = (_Float16)x2.y;
                s_xh[k] = r; s_ia[k] = r;
            }
        }
        __syncthreads();
    }
}

extern "C" void kernel_launch(void* const* d_in, const int* in_sizes, int n_in,
                              void* d_out, int out_size, void* d_ws, size_t ws_size,
                              hipStream_t stream) {
    const float* seq1  = (const float*)d_in[0];
    const float* seq2  = (const float*)d_in[1];
    const float* mask1 = (const float*)d_in[2];
    const float* mask2 = (const float*)d_in[3];
    const float* W1    = (const float*)d_in[4];
    const float* W2    = (const float*)d_in[5];
    const float* v     = (const float*)d_in[6];
    const float* Wg    = (const float*)d_in[7];
    const float* bg    = (const float*)d_in[8];
    const float* wih   = (const float*)d_in[9];
    const float* whh   = (const float*)d_in[10];
    const float* bih   = (const float*)d_in[11];
    const float* bhh   = (const float*)d_in[12];

    half2_v* ws = (half2_v*)d_ws;
    prep_pack<<<dim3((N_PACK + 255)/256), dim3(256), 0, stream>>>(W2, Wg, wih, whh, ws);
    prep_s2p<<<dim3(1024), dim3(256), 0, stream>>>(seq2, W1, (_Float16*)d_ws);
    match_rnn<<<dim3(NB), dim3(1024), 0, stream>>>(seq1, seq2, mask1, mask2,
                                                   v, bg, bih, bhh, ws, (float*)d_out);
}